// Round 7
// baseline (743.762 us; speedup 1.0000x reference)
//
#include <hip/hip_runtime.h>
#include <cstdint>
#include <cstddef>

// ---------------- problem constants ----------------
constexpr int BSZ = 32;
constexpr int T   = 1024;
constexpr int ID  = 256;
constexpr int MD  = 8;
constexpr int ORD = 256;
constexpr int HID = 512;
constexpr int BD  = BSZ * MD;   // 256
constexpr int CH  = 64;
constexpr int NQ  = T / CH;     // 16
constexpr int DO  = MD * ORD;   // 2048
constexpr int OO  = ORD * ORD;  // 65536
constexpr int KTOT24 = CH + ORD; // 320

typedef unsigned short ushort_t;
typedef __attribute__((ext_vector_type(8))) short bf16x8;
typedef __attribute__((ext_vector_type(8))) unsigned short us8;
typedef __attribute__((ext_vector_type(4))) float f32x4;

__device__ inline ushort_t f2bf(float f) {
    union { float f; uint32_t u; } v; v.f = f;
    uint32_t r = v.u + 0x7fffu + ((v.u >> 16) & 1u);
    return (ushort_t)(r >> 16);
}

// async global->LDS, 16B per lane; LDS dest = wave-uniform base + lane*16
__device__ inline void gl_lds16(const void* g, void* l) {
    __builtin_amdgcn_global_load_lds(
        (const __attribute__((address_space(1))) void*)g,
        (__attribute__((address_space(3))) void*)l, 16, 0, 0);
}

// ---------------- workspace layout (bytes) ----------------
constexpr size_t AL = 256;
constexpr size_t alup(size_t x) { return (x + AL - 1) & ~(AL - 1); }
constexpr size_t OFF_U2   = 0;                                          // f32 BD*T (dead after k_lend; reused for A256/A512)
constexpr size_t OFF_P    = alup(OFF_U2   + (size_t)BD * T * 4);        // f32 CH*ORD
constexpr size_t OFF_APOW = alup(OFF_P    + (size_t)CH * ORD * 4);      // f32 (CH+1)*OO (slot 0 reused for A128)
constexpr size_t OFF_MQ   = alup(OFF_APOW + (size_t)(CH + 1) * OO * 4); // f32 NQ*BD*ORD (scan buffer A)
constexpr size_t OFF_LEND = alup(OFF_MQ   + (size_t)NQ * BD * ORD * 4); // f32 NQ*BD*ORD (scan buffer B)
constexpr size_t OFF_U2B  = alup(OFF_LEND + (size_t)NQ * BD * ORD * 4); // bf16 BD*T
constexpr size_t OFF_PTRB = alup(OFF_U2B  + (size_t)BD * T * 2);        // bf16 (CH*ORD)*CH
constexpr size_t OFF_APB  = alup(OFF_PTRB + (size_t)CH * ORD * CH * 2); // bf16 CH*ORD*ORD
constexpr size_t OFF_WHBT = alup(OFF_APB  + (size_t)CH * ORD * ORD * 2);// bf16 HID*DO
constexpr size_t OFF_MQB  = alup(OFF_WHBT + (size_t)HID * DO * 2);      // bf16 NQ*BD*ORD
constexpr size_t OFF_MBUF = alup(OFF_MQB  + (size_t)NQ * BD * ORD * 2); // bf16 G*T*DO

// ---------------- U2[bd][t] (f32 + bf16), float4 x loads ----------------
__global__ __launch_bounds__(256) void k_u(const float* __restrict__ x,
                                           const float* __restrict__ kern,
                                           float* __restrict__ U2,
                                           ushort_t* __restrict__ U2b) {
    __shared__ float xs[32][ID + 1];
    __shared__ float ks[ID][MD];
    const int blk = blockIdx.x;
    const int b   = blk / (T / 32);
    const int t0  = (blk % (T / 32)) * 32;
    const int tid = threadIdx.x;

    for (int i = tid; i < ID * MD; i += 256) ks[i / MD][i % MD] = kern[i];
    const float* xp = x + ((size_t)b * T + t0) * ID;
    for (int i = tid; i < (32 * ID) / 4; i += 256) {
        float4 v = ((const float4*)xp)[i];
        int r = i >> 6, c = (i & 63) * 4;
        xs[r][c] = v.x; xs[r][c + 1] = v.y; xs[r][c + 2] = v.z; xs[r][c + 3] = v.w;
    }
    __syncthreads();

    const int d  = tid / 32;
    const int tl = tid % 32;
    float acc = 0.f;
    #pragma unroll 8
    for (int i = 0; i < ID; ++i) acc += xs[tl][i] * ks[i][d];
    size_t idx = ((size_t)b * MD + d) * T + t0 + tl;
    U2[idx]  = acc;
    U2b[idx] = f2bf(acc);
}

// ---------------- A -> Apow[1] (copy) + Apb slot 0 (transpose, bf16) ------
__global__ __launch_bounds__(256) void k_copyAT(const float* __restrict__ A,
                                                float* __restrict__ Apow,
                                                ushort_t* __restrict__ Apb) {
    __shared__ float t[32][33];
    const int o0 = blockIdx.x * 32, p0 = blockIdx.y * 32;
    const int tx = threadIdx.x & 31, ty = threadIdx.x >> 5;
    #pragma unroll
    for (int p = 0; p < 4; ++p) {
        int r = ty + p * 8;
        float v = A[(size_t)(p0 + r) * ORD + o0 + tx];
        Apow[OO + (size_t)(p0 + r) * ORD + o0 + tx] = v;
        t[r][tx] = v;
    }
    __syncthreads();
    #pragma unroll
    for (int p = 0; p < 4; ++p) {
        int r = ty + p * 8;
        Apb[(size_t)(o0 + r) * ORD + p0 + tx] = f2bf(t[tx][r]);
    }
}

// ---------------- doubling: Apow[n+z+1] = Apow[z+1] @ Apow[n] -------------
// Also emits Apb[(e-1)] = bf16(A^e)^T for the MFMA B-operand.
__global__ __launch_bounds__(256) void k_pow(float* __restrict__ Apow, int n,
                                             ushort_t* __restrict__ Apb) {
    __shared__ float As[16][65];
    __shared__ float Bs[16][65];
    const int z    = blockIdx.z;
    const int row0 = blockIdx.y * 64;
    const int col0 = blockIdx.x * 64;
    const int tid  = threadIdx.x;
    const int tx = tid & 15, ty = tid >> 4;
    const float* Ag = Apow + (size_t)(z + 1) * OO;
    const float* Bg = Apow + (size_t)n * OO;
    float*       Cg = Apow + (size_t)(n + z + 1) * OO;

    float acc[4][4] = {};
    for (int k0 = 0; k0 < ORD; k0 += 16) {
        for (int i = tid; i < 64 * 16; i += 256) {
            int m = i >> 4, kk = i & 15;
            As[kk][m] = Ag[(size_t)(row0 + m) * ORD + k0 + kk];
        }
        for (int i = tid; i < 16 * 64; i += 256) {
            int kk = i >> 6, n2 = i & 63;
            Bs[kk][n2] = Bg[(size_t)(k0 + kk) * ORD + col0 + n2];
        }
        __syncthreads();
        #pragma unroll
        for (int kk = 0; kk < 16; ++kk) {
            float a[4], b[4];
            #pragma unroll
            for (int i = 0; i < 4; ++i) a[i] = As[kk][ty * 4 + i];
            #pragma unroll
            for (int j = 0; j < 4; ++j) b[j] = Bs[kk][tx * 4 + j];
            #pragma unroll
            for (int i = 0; i < 4; ++i)
                #pragma unroll
                for (int j = 0; j < 4; ++j) acc[i][j] += a[i] * b[j];
        }
        __syncthreads();
    }
    ushort_t* ap = Apb + (size_t)(n + z) * OO;   // slot e-1, e = n+z+1
    #pragma unroll
    for (int i = 0; i < 4; ++i) {
        float4 v = make_float4(acc[i][0], acc[i][1], acc[i][2], acc[i][3]);
        *(float4*)&Cg[(size_t)(row0 + ty * 4 + i) * ORD + col0 + tx * 4] = v;
        #pragma unroll
        for (int j = 0; j < 4; ++j)
            ap[(size_t)(col0 + tx * 4 + j) * ORD + row0 + ty * 4 + i] = f2bf(acc[i][j]);
    }
}

// ---------------- generic 256x256 f32 matmul: C = A @ B ----------------
__global__ __launch_bounds__(256) void k_sq(const float* __restrict__ Ag,
                                            const float* __restrict__ Bg,
                                            float* __restrict__ Cg) {
    __shared__ float As[16][65];
    __shared__ float Bs[16][65];
    const int row0 = blockIdx.y * 64;
    const int col0 = blockIdx.x * 64;
    const int tid  = threadIdx.x;
    const int tx = tid & 15, ty = tid >> 4;

    float acc[4][4] = {};
    for (int k0 = 0; k0 < ORD; k0 += 16) {
        for (int i = tid; i < 64 * 16; i += 256) {
            int m = i >> 4, kk = i & 15;
            As[kk][m] = Ag[(size_t)(row0 + m) * ORD + k0 + kk];
        }
        for (int i = tid; i < 16 * 64; i += 256) {
            int kk = i >> 6, n2 = i & 63;
            Bs[kk][n2] = Bg[(size_t)(k0 + kk) * ORD + col0 + n2];
        }
        __syncthreads();
        #pragma unroll
        for (int kk = 0; kk < 16; ++kk) {
            float a[4], b[4];
            #pragma unroll
            for (int i = 0; i < 4; ++i) a[i] = As[kk][ty * 4 + i];
            #pragma unroll
            for (int j = 0; j < 4; ++j) b[j] = Bs[kk][tx * 4 + j];
            #pragma unroll
            for (int i = 0; i < 4; ++i)
                #pragma unroll
                for (int j = 0; j < 4; ++j) acc[i][j] += a[i] * b[j];
        }
        __syncthreads();
    }
    #pragma unroll
    for (int i = 0; i < 4; ++i) {
        float4 v = make_float4(acc[i][0], acc[i][1], acc[i][2], acc[i][3]);
        *(float4*)&Cg[(size_t)(row0 + ty * 4 + i) * ORD + col0 + tx * 4] = v;
    }
}

// ---------------- P[k] = Brow @ A^k ----------------
__global__ __launch_bounds__(256) void k_p(const float* __restrict__ Brow,
                                           const float* __restrict__ Apow,
                                           float* __restrict__ P) {
    __shared__ float br[ORD];
    const int k = blockIdx.x;
    const int o = threadIdx.x;
    br[o] = Brow[o];
    __syncthreads();
    if (k == 0) { P[o] = br[o]; return; }
    const float* M = Apow + (size_t)k * OO;
    float acc = 0.f;
    #pragma unroll 4
    for (int op = 0; op < ORD; ++op) acc += br[op] * M[(size_t)op * ORD + o];
    P[(size_t)k * ORD + o] = acc;
}

// ---------------- Ptrib[col=(c,o)][j] = bf16(P[c-j][o]) or 0 --------------
__global__ __launch_bounds__(256) void k_ptrib(const float* __restrict__ P,
                                               ushort_t* __restrict__ Ptrib) {
    int idx = blockIdx.x * 256 + threadIdx.x;   // (CH*ORD)*CH
    int col = idx >> 6, j = idx & (CH - 1);
    int c = col >> 8, o = col & 255;
    float v = (j <= c) ? P[(size_t)(c - j) * ORD + o] : 0.f;
    Ptrib[idx] = f2bf(v);
}

// ---------------- Whbt[col][k] = bf16(Wh[k][col]) — LDS-tiled -------------
__global__ __launch_bounds__(256) void k_whbt(const float* __restrict__ Wh,
                                              ushort_t* __restrict__ Whbt) {
    __shared__ float t[32][33];
    const int k0 = blockIdx.x * 32;   // over DO
    const int h0 = blockIdx.y * 32;   // over HID
    const int tx = threadIdx.x & 31, ty = threadIdx.x >> 5;
    #pragma unroll
    for (int p = 0; p < 4; ++p) {
        int r = ty + p * 8;
        t[r][tx] = Wh[(size_t)(k0 + r) * HID + h0 + tx];
    }
    __syncthreads();
    #pragma unroll
    for (int p = 0; p < 4; ++p) {
        int r = ty + p * 8;
        Whbt[(size_t)(h0 + r) * DO + k0 + tx] = f2bf(t[tx][r]);
    }
}

// ---- Lend[q] = U2-chunk @ Prev  (f32); also inits scan: M[q+1]=Lend[q], M[0]=0
__global__ __launch_bounds__(256) void k_lend(const float* __restrict__ U2,
                                              const float* __restrict__ P,
                                              float* __restrict__ Lend,
                                              float* __restrict__ MqA) {
    __shared__ float As[16][65];
    __shared__ float Bs[16][65];
    const int q    = blockIdx.z;
    const int row0 = blockIdx.y * 64;
    const int col0 = blockIdx.x * 64;
    const int tid  = threadIdx.x;
    const int tx = tid & 15, ty = tid >> 4;

    float acc[4][4] = {};
    for (int k0 = 0; k0 < CH; k0 += 16) {
        for (int i = tid; i < 64 * 16; i += 256) {
            int m = i >> 4, kk = i & 15;
            As[kk][m] = U2[(size_t)(row0 + m) * T + q * CH + k0 + kk];
        }
        for (int i = tid; i < 16 * 64; i += 256) {
            int kk = i >> 6, n2 = i & 63;
            Bs[kk][n2] = P[(size_t)(CH - 1 - (k0 + kk)) * ORD + col0 + n2];
        }
        __syncthreads();
        #pragma unroll
        for (int kk = 0; kk < 16; ++kk) {
            float a[4], b[4];
            #pragma unroll
            for (int i = 0; i < 4; ++i) a[i] = As[kk][ty * 4 + i];
            #pragma unroll
            for (int j = 0; j < 4; ++j) b[j] = Bs[kk][tx * 4 + j];
            #pragma unroll
            for (int i = 0; i < 4; ++i)
                #pragma unroll
                for (int j = 0; j < 4; ++j) acc[i][j] += a[i] * b[j];
        }
        __syncthreads();
    }
    #pragma unroll
    for (int i = 0; i < 4; ++i) {
        float4 v = make_float4(acc[i][0], acc[i][1], acc[i][2], acc[i][3]);
        size_t off = (size_t)(row0 + ty * 4 + i) * ORD + col0 + tx * 4;
        *(float4*)&Lend[(size_t)q * (BD * ORD) + off] = v;
        if (q + 1 < NQ) *(float4*)&MqA[(size_t)(q + 1) * (BD * ORD) + off] = v;
        if (q == 0) {
            float4 z = make_float4(0.f, 0.f, 0.f, 0.f);
            *(float4*)&MqA[off] = z;
        }
    }
}

// ---- scan step: Mout[q] = Min[q] + Min[q-stride] @ Pw; dstb!=0 -> bf16 only
__global__ __launch_bounds__(256) void k_scan(const float* __restrict__ Min,
                                              float* __restrict__ Mout,
                                              const float* __restrict__ Pw,
                                              int stride,
                                              ushort_t* __restrict__ dstb) {
    const int q    = blockIdx.z;
    const int row0 = blockIdx.y * 64;
    const int col0 = blockIdx.x * 64;
    const int tid  = threadIdx.x;
    const float* src = Min + (size_t)q * (BD * ORD);
    float*       dst = Mout + (size_t)q * (BD * ORD);
    ushort_t*    db  = dstb ? dstb + (size_t)q * (BD * ORD) : nullptr;

    if (q - stride < 1) {   // nothing to add (M_0 = 0 source) -> copy through
        for (int i = tid; i < 64 * 64; i += 256) {
            int r = i >> 6, c = i & 63;
            size_t off = (size_t)(row0 + r) * ORD + col0 + c;
            float v = src[off];
            if (db) db[off] = f2bf(v); else dst[off] = v;
        }
        return;
    }

    __shared__ float As[16][65];
    __shared__ float Bs[16][65];
    const int tx = tid & 15, ty = tid >> 4;
    const float* Ag = Min + (size_t)(q - stride) * (BD * ORD);

    float acc[4][4] = {};
    for (int k0 = 0; k0 < ORD; k0 += 16) {
        for (int i = tid; i < 64 * 16; i += 256) {
            int m = i >> 4, kk = i & 15;
            As[kk][m] = Ag[(size_t)(row0 + m) * ORD + k0 + kk];
        }
        for (int i = tid; i < 16 * 64; i += 256) {
            int kk = i >> 6, n2 = i & 63;
            Bs[kk][n2] = Pw[(size_t)(k0 + kk) * ORD + col0 + n2];
        }
        __syncthreads();
        #pragma unroll
        for (int kk = 0; kk < 16; ++kk) {
            float a[4], b[4];
            #pragma unroll
            for (int i = 0; i < 4; ++i) a[i] = As[kk][ty * 4 + i];
            #pragma unroll
            for (int j = 0; j < 4; ++j) b[j] = Bs[kk][tx * 4 + j];
            #pragma unroll
            for (int i = 0; i < 4; ++i)
                #pragma unroll
                for (int j = 0; j < 4; ++j) acc[i][j] += a[i] * b[j];
        }
        __syncthreads();
    }
    #pragma unroll
    for (int i = 0; i < 4; ++i) {
        int row = row0 + ty * 4 + i;
        #pragma unroll
        for (int j = 0; j < 4; ++j) {
            int o = col0 + tx * 4 + j;
            size_t off = (size_t)row * ORD + o;
            float val = acc[i][j] + src[off];
            if (db) db[off] = f2bf(val); else dst[off] = val;
        }
    }
}

// ====== MFMA GEMM 1 (2-phase dbuf): mbuf = [U2chunk | Mq] @ [Ptrib ; Apb] ==
__global__ __launch_bounds__(256) void k_gemm24(const ushort_t* __restrict__ U2b,
                                                const ushort_t* __restrict__ Mqb,
                                                const ushort_t* __restrict__ Ptrib,
                                                const ushort_t* __restrict__ Apb,
                                                ushort_t* __restrict__ mbuf,
                                                int gbase, int nrows) {
    __shared__ ushort_t As[2][128 * 32];
    __shared__ ushort_t Bs[2][128 * 32];
    const int q       = blockIdx.z;
    const int rowbase = blockIdx.y * 128;
    const int colbase = blockIdx.x * 128;
    const int tid  = threadIdx.x;
    const int lane = tid & 63;
    const int wid  = tid >> 6;
    const int wr = wid >> 1, wc = wid & 1;
    const int lr = lane & 15, lk = (lane >> 4) * 8;

    int ub[2], rowu[2], cbu[2], garow[2];
    #pragma unroll
    for (int i = 0; i < 2; ++i) {
        ub[i] = (wid * 2 + i) * 64;
        int u = ub[i] + lane;
        rowu[i] = u >> 2; cbu[i] = (u & 3) * 8;
        int gr = rowbase + rowu[i]; if (gr >= nrows) gr = nrows - 1;
        garow[i] = gbase + gr;
    }

    auto STAGE = [&](int buf, int s) {
        const int k0 = s * 32;
        #pragma unroll
        for (int i = 0; i < 2; ++i) {
            const ushort_t *ga, *gb;
            if (k0 < CH) {
                ga = &U2b[(size_t)garow[i] * T + q * CH + k0 + cbu[i]];
                gb = &Ptrib[(size_t)(colbase + rowu[i]) * CH + k0 + cbu[i]];
            } else {
                ga = &Mqb[((size_t)q * BD + garow[i]) * ORD + (k0 - CH) + cbu[i]];
                gb = &Apb[(size_t)(colbase + rowu[i]) * ORD + (k0 - CH) + cbu[i]];
            }
            gl_lds16(ga, &As[buf][ub[i] * 8]);
            gl_lds16(gb, &Bs[buf][ub[i] * 8]);
        }
    };

    f32x4 acc[4][4];
    #pragma unroll
    for (int m = 0; m < 4; ++m)
        #pragma unroll
        for (int n = 0; n < 4; ++n) acc[m][n] = 0.f;

    auto COMPUTE = [&](int buf) {
        bf16x8 af[4], bfv[4];
        #pragma unroll
        for (int m = 0; m < 4; ++m)
            af[m]  = *(const bf16x8*)&As[buf][(wr * 64 + m * 16 + lr) * 32 + lk];
        #pragma unroll
        for (int n = 0; n < 4; ++n)
            bfv[n] = *(const bf16x8*)&Bs[buf][(wc * 64 + n * 16 + lr) * 32 + lk];
        #pragma unroll
        for (int m = 0; m < 4; ++m)
            #pragma unroll
            for (int n = 0; n < 4; ++n)
                acc[m][n] = __builtin_amdgcn_mfma_f32_16x16x32_bf16(af[m], bfv[n], acc[m][n], 0, 0, 0);
    };

    STAGE(0, 0);
    __syncthreads();
    int cur = 0;
    for (int s = 0; s < KTOT24 / 32 - 1; ++s) {
        STAGE(cur ^ 1, s + 1);
        COMPUTE(cur);
        __syncthreads();
        cur ^= 1;
    }
    COMPUTE(cur);

    #pragma unroll
    for (int m = 0; m < 4; ++m) {
        #pragma unroll
        for (int n = 0; n < 4; ++n) {
            int colv = colbase + wc * 64 + n * 16 + lr;
            int c = colv >> 8, o = colv & 255;
            #pragma unroll
            for (int r = 0; r < 4; ++r) {
                int grow = rowbase + wr * 64 + m * 16 + ((lane >> 4) << 2) + r;
                if (grow < nrows) {
                    int bl = grow >> 3, d = grow & 7;
                    mbuf[((size_t)(bl * T + q * CH + c)) * DO + (d << 8) + o] =
                        f2bf(acc[m][n][r]);
                }
            }
        }
    }
}

// ====== MFMA GEMM 2 (2-phase dbuf): out = tanh(mbuf @ Wh + bh) ======
__global__ __launch_bounds__(256) void k_gemm5(const ushort_t* __restrict__ mbuf,
                                               const ushort_t* __restrict__ Whbt,
                                               const float* __restrict__ bh,
                                               float* __restrict__ out, int gy) {
    __shared__ ushort_t As[2][128 * 32];
    __shared__ ushort_t Bs[2][128 * 32];
    int wg = blockIdx.x;
    int bx, by;
    if ((gy & 7) == 0) {
        int xcd = wg & 7, j = wg >> 3;
        int rpx = gy >> 3;                 // row panels per XCD
        by = xcd * rpx + (j >> 2);
        bx = j & 3;
    } else { bx = wg & 3; by = wg >> 2; }
    const int rowbase = by * 128;
    const int colbase = bx * 128;
    const int tid  = threadIdx.x;
    const int lane = tid & 63;
    const int wid  = tid >> 6;
    const int wr = wid >> 1, wc = wid & 1;
    const int lr = lane & 15, lk = (lane >> 4) * 8;

    int ub[2];
    const ushort_t *ga[2], *gb[2];
    #pragma unroll
    for (int i = 0; i < 2; ++i) {
        ub[i] = (wid * 2 + i) * 64;
        int u = ub[i] + lane;
        int row = u >> 2, cb = (u & 3) * 8;
        ga[i] = &mbuf[(size_t)(rowbase + row) * DO + cb];
        gb[i] = &Whbt[(size_t)(colbase + row) * DO + cb];
    }

    auto STAGE = [&](int buf, int s) {
        const int k0 = s * 32;
        #pragma unroll
        for (int i = 0; i < 2; ++i) {
            gl_lds16(ga[i] + k0, &As[buf][ub[i] * 8]);
            gl_lds16(gb[i] + k0, &Bs[buf][ub[i] * 8]);
        }
    };

    f32x4 acc[4][4];
    #pragma unroll
    for (int m = 0; m < 4; ++m)
        #pragma unroll
        for (int n = 0; n < 4; ++n) acc[m][n] = 0.f;

    auto COMPUTE = [&](int buf) {
        bf16x8 af[4], bfv[4];
        #pragma unroll
        for (int m = 0; m < 4; ++m)
            af[m]  = *(const bf16x8*)&As[buf][(wr * 64 + m * 16 + lr) * 32 + lk];
        #pragma unroll
        for (int n = 0; n < 4; ++n)
            bfv[n] = *(const bf16x8*)&Bs[buf][(wc * 64 + n * 16 + lr) * 32 + lk];
        #pragma unroll
        for (int m = 0; m < 4; ++m)
            #pragma unroll
            for (int n = 0; n < 4; ++n)
                acc[m][n] = __builtin_amdgcn_mfma_f32_16x16x32_bf16(af[m], bfv[n], acc[m][n], 0, 0, 0);
    };

    STAGE(0, 0);
    __syncthreads();
    int cur = 0;
    for (int s = 0; s < DO / 32 - 1; ++s) {
        STAGE(cur ^ 1, s + 1);
        COMPUTE(cur);
        __syncthreads();
        cur ^= 1;
    }
    COMPUTE(cur);

    #pragma unroll
    for (int m = 0; m < 4; ++m) {
        #pragma unroll
        for (int n = 0; n < 4; ++n) {
            int col = colbase + wc * 64 + n * 16 + lr;
            float bias = bh[col];
            #pragma unroll
            for (int r = 0; r < 4; ++r) {
                int grow = rowbase + wr * 64 + m * 16 + ((lane >> 4) << 2) + r;
                out[(size_t)grow * HID + col] = tanhf(acc[m][n][r] + bias);
            }
        }
    }
}

// ---------------- launch ----------------
extern "C" void kernel_launch(void* const* d_in, const int* in_sizes, int n_in,
                              void* d_out, int out_size, void* d_ws, size_t ws_size,
                              hipStream_t stream) {
    const float* x    = (const float*)d_in[0];
    const float* kern = (const float*)d_in[1];
    const float* Wh   = (const float*)d_in[2];
    const float* bh   = (const float*)d_in[3];
    const float* A    = (const float*)d_in[4];
    const float* Brow = (const float*)d_in[5];
    float* out = (float*)d_out;

    char* base = (char*)d_ws;
    float*    U2    = (float*)(base + OFF_U2);
    float*    P     = (float*)(base + OFF_P);
    float*    Apow  = (float*)(base + OFF_APOW);
    float*    MqA   = (float*)(base + OFF_MQ);
    float*    Lend  = (float*)(base + OFF_LEND);
    ushort_t* U2b   = (ushort_t*)(base + OFF_U2B);
    ushort_t* Ptrib = (ushort_t*)(base + OFF_PTRB);
    ushort_t* Apb   = (ushort_t*)(base + OFF_APB);
    ushort_t* Whbt  = (ushort_t*)(base + OFF_WHBT);
    ushort_t* Mqb   = (ushort_t*)(base + OFF_MQB);
    ushort_t* mbuf  = (ushort_t*)(base + OFF_MBUF);

    // scratch for higher powers (regions dead by the time they're written)
    float* A64  = Apow + (size_t)CH * OO;  // A^64 (slot 64)
    float* A128 = Apow;                    // Apow slot 0 (unused)
    float* A256 = U2;                      // U2 f32 dead after k_lend
    float* A512 = U2 + OO;

    // choose largest batch group whose bf16 mbuf fits
    int G = 1;
    for (int g = 32; g >= 1; g >>= 1) {
        if (OFF_MBUF + (size_t)g * T * DO * 2 <= ws_size) { G = g; break; }
    }
    const int ngroups = BSZ / G;

    // U projection (f32 + bf16)
    k_u<<<dim3(BSZ * (T / 32)), 256, 0, stream>>>(x, kern, U2, U2b);

    // A -> Apow[1] + Apb[0]; powers 2..64 by doubling (f32 + bf16 transpose)
    k_copyAT<<<dim3(8, 8), 256, 0, stream>>>(A, Apow, Apb);
    for (int n = 1; n < CH; n <<= 1)
        k_pow<<<dim3(4, 4, n), 256, 0, stream>>>(Apow, n, Apb);

    // P rows (f32), bf16 operand prep
    k_p<<<dim3(CH), 256, 0, stream>>>(Brow, Apow, P);
    k_ptrib<<<dim3((CH * ORD * CH) / 256), 256, 0, stream>>>(P, Ptrib);
    k_whbt<<<dim3(DO / 32, HID / 32), 256, 0, stream>>>(Wh, Whbt);

    // chunk-end partials (f32) + scan init — last use of U2 f32
    k_lend<<<dim3(ORD / 64, BD / 64, NQ), 256, 0, stream>>>(U2, P, Lend, MqA);

    // Hillis-Steele matrix scan for M_q (f32), strides 1,2,4,8
    k_sq<<<dim3(4, 4), 256, 0, stream>>>(A64,  A64,  A128);
    k_sq<<<dim3(4, 4), 256, 0, stream>>>(A128, A128, A256);
    k_sq<<<dim3(4, 4), 256, 0, stream>>>(A256, A256, A512);
    k_scan<<<dim3(4, 4, NQ), 256, 0, stream>>>(MqA, Lend, A64, 1, nullptr);
    k_scan<<<dim3(4, 4, NQ), 256, 0, stream>>>(Lend, MqA, A128, 2, nullptr);
    k_scan<<<dim3(4, 4, NQ), 256, 0, stream>>>(MqA, Lend, A256, 4, nullptr);
    k_scan<<<dim3(4, 4, NQ), 256, 0, stream>>>(Lend, MqA, A512, 8, Mqb);

    // per batch-group: MFMA m-materialization + MFMA output GEMM
    for (int g = 0; g < ngroups; ++g) {
        const int gbase = g * G * MD;
        const int nrows = G * MD;
        const int gy24  = (nrows + 127) / 128;
        k_gemm24<<<dim3((CH * ORD) / 128, gy24, NQ), 256, 0, stream>>>(
            U2b, Mqb, Ptrib, Apb, mbuf, gbase, nrows);
        const int gy = (G * T) / 128;
        k_gemm5<<<dim3(4 * gy), 256, 0, stream>>>(
            mbuf, Whbt, bh, out + (size_t)g * G * T * HID, gy);
    }
}

// Round 8
// 615.032 us; speedup vs baseline: 1.2093x; 1.2093x over previous
//
#include <hip/hip_runtime.h>
#include <cstdint>
#include <cstddef>

// ---------------- problem constants ----------------
constexpr int BSZ = 32;
constexpr int T   = 1024;
constexpr int ID  = 256;
constexpr int MD  = 8;
constexpr int ORD = 256;
constexpr int HID = 512;
constexpr int BD  = BSZ * MD;   // 256
constexpr int CH  = 64;
constexpr int NQ  = T / CH;     // 16
constexpr int DO  = MD * ORD;   // 2048
constexpr int OO  = ORD * ORD;  // 65536
constexpr int KTOT24 = CH + ORD; // 320

typedef unsigned short ushort_t;
typedef __attribute__((ext_vector_type(8))) short bf16x8;
typedef __attribute__((ext_vector_type(8))) unsigned short us8;
typedef __attribute__((ext_vector_type(4))) float f32x4;

__device__ inline ushort_t f2bf(float f) {
    union { float f; uint32_t u; } v; v.f = f;
    uint32_t r = v.u + 0x7fffu + ((v.u >> 16) & 1u);
    return (ushort_t)(r >> 16);
}

// async global->LDS, 16B per lane; LDS dest = wave-uniform base + lane*16
__device__ inline void gl_lds16(const void* g, void* l) {
    __builtin_amdgcn_global_load_lds(
        (const __attribute__((address_space(1))) void*)g,
        (__attribute__((address_space(3))) void*)l, 16, 0, 0);
}

// ---------------- workspace layout (bytes) ----------------
constexpr size_t AL = 256;
constexpr size_t alup(size_t x) { return (x + AL - 1) & ~(AL - 1); }
constexpr size_t OFF_U2   = 0;                                          // f32 BD*T (dead after k_lend; reused for A256/A512)
constexpr size_t OFF_P    = alup(OFF_U2   + (size_t)BD * T * 4);        // f32 CH*ORD
constexpr size_t OFF_APOW = alup(OFF_P    + (size_t)CH * ORD * 4);      // f32 (CH+1)*OO (slot 0 reused for A128)
constexpr size_t OFF_MQ   = alup(OFF_APOW + (size_t)(CH + 1) * OO * 4); // f32 NQ*BD*ORD (scan buffer A)
constexpr size_t OFF_LEND = alup(OFF_MQ   + (size_t)NQ * BD * ORD * 4); // f32 NQ*BD*ORD (scan buffer B)
constexpr size_t OFF_U2B  = alup(OFF_LEND + (size_t)NQ * BD * ORD * 4); // bf16 BD*T
constexpr size_t OFF_PTRB = alup(OFF_U2B  + (size_t)BD * T * 2);        // bf16 (CH*ORD)*CH
constexpr size_t OFF_APB  = alup(OFF_PTRB + (size_t)CH * ORD * CH * 2); // bf16 CH*ORD*ORD
constexpr size_t OFF_WHBT = alup(OFF_APB  + (size_t)CH * ORD * ORD * 2);// bf16 HID*DO
constexpr size_t OFF_MQB  = alup(OFF_WHBT + (size_t)HID * DO * 2);      // bf16 NQ*BD*ORD
constexpr size_t OFF_MBUF = alup(OFF_MQB  + (size_t)NQ * BD * ORD * 2); // bf16 G*T*DO

// ---------------- U2[bd][t] (f32 + bf16), float4 x loads ----------------
__global__ __launch_bounds__(256) void k_u(const float* __restrict__ x,
                                           const float* __restrict__ kern,
                                           float* __restrict__ U2,
                                           ushort_t* __restrict__ U2b) {
    __shared__ float xs[32][ID + 1];
    __shared__ float ks[ID][MD];
    const int blk = blockIdx.x;
    const int b   = blk / (T / 32);
    const int t0  = (blk % (T / 32)) * 32;
    const int tid = threadIdx.x;

    for (int i = tid; i < ID * MD; i += 256) ks[i / MD][i % MD] = kern[i];
    const float* xp = x + ((size_t)b * T + t0) * ID;
    for (int i = tid; i < (32 * ID) / 4; i += 256) {
        float4 v = ((const float4*)xp)[i];
        int r = i >> 6, c = (i & 63) * 4;
        xs[r][c] = v.x; xs[r][c + 1] = v.y; xs[r][c + 2] = v.z; xs[r][c + 3] = v.w;
    }
    __syncthreads();

    const int d  = tid / 32;
    const int tl = tid % 32;
    float acc = 0.f;
    #pragma unroll 8
    for (int i = 0; i < ID; ++i) acc += xs[tl][i] * ks[i][d];
    size_t idx = ((size_t)b * MD + d) * T + t0 + tl;
    U2[idx]  = acc;
    U2b[idx] = f2bf(acc);
}

// ---------------- A -> Apow[1] (copy) + Apb slot 0 (transpose, bf16) ------
__global__ __launch_bounds__(256) void k_copyAT(const float* __restrict__ A,
                                                float* __restrict__ Apow,
                                                ushort_t* __restrict__ Apb) {
    __shared__ float t[32][33];
    const int o0 = blockIdx.x * 32, p0 = blockIdx.y * 32;
    const int tx = threadIdx.x & 31, ty = threadIdx.x >> 5;
    #pragma unroll
    for (int p = 0; p < 4; ++p) {
        int r = ty + p * 8;
        float v = A[(size_t)(p0 + r) * ORD + o0 + tx];
        Apow[OO + (size_t)(p0 + r) * ORD + o0 + tx] = v;
        t[r][tx] = v;
    }
    __syncthreads();
    #pragma unroll
    for (int p = 0; p < 4; ++p) {
        int r = ty + p * 8;
        Apb[(size_t)(o0 + r) * ORD + p0 + tx] = f2bf(t[tx][r]);
    }
}

// ---------------- doubling: Apow[n+z+1] = Apow[z+1] @ Apow[n] -------------
// Also emits Apb[(e-1)] = bf16(A^e)^T for the MFMA B-operand.
__global__ __launch_bounds__(256) void k_pow(float* __restrict__ Apow, int n,
                                             ushort_t* __restrict__ Apb) {
    __shared__ float As[16][65];
    __shared__ float Bs[16][65];
    const int z    = blockIdx.z;
    const int row0 = blockIdx.y * 64;
    const int col0 = blockIdx.x * 64;
    const int tid  = threadIdx.x;
    const int tx = tid & 15, ty = tid >> 4;
    const float* Ag = Apow + (size_t)(z + 1) * OO;
    const float* Bg = Apow + (size_t)n * OO;
    float*       Cg = Apow + (size_t)(n + z + 1) * OO;

    float acc[4][4] = {};
    for (int k0 = 0; k0 < ORD; k0 += 16) {
        for (int i = tid; i < 64 * 16; i += 256) {
            int m = i >> 4, kk = i & 15;
            As[kk][m] = Ag[(size_t)(row0 + m) * ORD + k0 + kk];
        }
        for (int i = tid; i < 16 * 64; i += 256) {
            int kk = i >> 6, n2 = i & 63;
            Bs[kk][n2] = Bg[(size_t)(k0 + kk) * ORD + col0 + n2];
        }
        __syncthreads();
        #pragma unroll
        for (int kk = 0; kk < 16; ++kk) {
            float a[4], b[4];
            #pragma unroll
            for (int i = 0; i < 4; ++i) a[i] = As[kk][ty * 4 + i];
            #pragma unroll
            for (int j = 0; j < 4; ++j) b[j] = Bs[kk][tx * 4 + j];
            #pragma unroll
            for (int i = 0; i < 4; ++i)
                #pragma unroll
                for (int j = 0; j < 4; ++j) acc[i][j] += a[i] * b[j];
        }
        __syncthreads();
    }
    ushort_t* ap = Apb + (size_t)(n + z) * OO;   // slot e-1, e = n+z+1
    #pragma unroll
    for (int i = 0; i < 4; ++i) {
        float4 v = make_float4(acc[i][0], acc[i][1], acc[i][2], acc[i][3]);
        *(float4*)&Cg[(size_t)(row0 + ty * 4 + i) * ORD + col0 + tx * 4] = v;
        #pragma unroll
        for (int j = 0; j < 4; ++j)
            ap[(size_t)(col0 + tx * 4 + j) * ORD + row0 + ty * 4 + i] = f2bf(acc[i][j]);
    }
}

// ---------------- P[k] = Brow @ A^k ----------------
__global__ __launch_bounds__(256) void k_p(const float* __restrict__ Brow,
                                           const float* __restrict__ Apow,
                                           float* __restrict__ P) {
    __shared__ float br[ORD];
    const int k = blockIdx.x;
    const int o = threadIdx.x;
    br[o] = Brow[o];
    __syncthreads();
    if (k == 0) { P[o] = br[o]; return; }
    const float* M = Apow + (size_t)k * OO;
    float acc = 0.f;
    #pragma unroll 4
    for (int op = 0; op < ORD; ++op) acc += br[op] * M[(size_t)op * ORD + o];
    P[(size_t)k * ORD + o] = acc;
}

// ---------------- Ptrib[col=(c,o)][j] = bf16(P[c-j][o]) or 0 --------------
__global__ __launch_bounds__(256) void k_ptrib(const float* __restrict__ P,
                                               ushort_t* __restrict__ Ptrib) {
    int idx = blockIdx.x * 256 + threadIdx.x;   // (CH*ORD)*CH
    int col = idx >> 6, j = idx & (CH - 1);
    int c = col >> 8, o = col & 255;
    float v = (j <= c) ? P[(size_t)(c - j) * ORD + o] : 0.f;
    Ptrib[idx] = f2bf(v);
}

// ---------------- Whbt[col][k] = bf16(Wh[k][col]) — LDS-tiled -------------
__global__ __launch_bounds__(256) void k_whbt(const float* __restrict__ Wh,
                                              ushort_t* __restrict__ Whbt) {
    __shared__ float t[32][33];
    const int k0 = blockIdx.x * 32;   // over DO
    const int h0 = blockIdx.y * 32;   // over HID
    const int tx = threadIdx.x & 31, ty = threadIdx.x >> 5;
    #pragma unroll
    for (int p = 0; p < 4; ++p) {
        int r = ty + p * 8;
        t[r][tx] = Wh[(size_t)(k0 + r) * HID + h0 + tx];
    }
    __syncthreads();
    #pragma unroll
    for (int p = 0; p < 4; ++p) {
        int r = ty + p * 8;
        Whbt[(size_t)(h0 + r) * DO + k0 + tx] = f2bf(t[tx][r]);
    }
}

// ---- Lend[q] = U2-chunk @ Prev  (f32); also inits scan: M[q+1]=Lend[q], M[0]=0
__global__ __launch_bounds__(256) void k_lend(const float* __restrict__ U2,
                                              const float* __restrict__ P,
                                              float* __restrict__ Lend,
                                              float* __restrict__ MqA) {
    __shared__ float As[16][65];
    __shared__ float Bs[16][65];
    const int q    = blockIdx.z;
    const int row0 = blockIdx.y * 64;
    const int col0 = blockIdx.x * 64;
    const int tid  = threadIdx.x;
    const int tx = tid & 15, ty = tid >> 4;

    float acc[4][4] = {};
    for (int k0 = 0; k0 < CH; k0 += 16) {
        for (int i = tid; i < 64 * 16; i += 256) {
            int m = i >> 4, kk = i & 15;
            As[kk][m] = U2[(size_t)(row0 + m) * T + q * CH + k0 + kk];
        }
        for (int i = tid; i < 16 * 64; i += 256) {
            int kk = i >> 6, n2 = i & 63;
            Bs[kk][n2] = P[(size_t)(CH - 1 - (k0 + kk)) * ORD + col0 + n2];
        }
        __syncthreads();
        #pragma unroll
        for (int kk = 0; kk < 16; ++kk) {
            float a[4], b[4];
            #pragma unroll
            for (int i = 0; i < 4; ++i) a[i] = As[kk][ty * 4 + i];
            #pragma unroll
            for (int j = 0; j < 4; ++j) b[j] = Bs[kk][tx * 4 + j];
            #pragma unroll
            for (int i = 0; i < 4; ++i)
                #pragma unroll
                for (int j = 0; j < 4; ++j) acc[i][j] += a[i] * b[j];
        }
        __syncthreads();
    }
    #pragma unroll
    for (int i = 0; i < 4; ++i) {
        float4 v = make_float4(acc[i][0], acc[i][1], acc[i][2], acc[i][3]);
        size_t off = (size_t)(row0 + ty * 4 + i) * ORD + col0 + tx * 4;
        *(float4*)&Lend[(size_t)q * (BD * ORD) + off] = v;
        if (q + 1 < NQ) *(float4*)&MqA[(size_t)(q + 1) * (BD * ORD) + off] = v;
        if (q == 0) {
            float4 z = make_float4(0.f, 0.f, 0.f, 0.f);
            *(float4*)&MqA[off] = z;
        }
    }
}

// ---- scan step: Mout[q] = Min[q] + Min[q-stride] @ Pw; dstb!=0 -> bf16 only
// Extra tile-group at blockIdx.z == NQ computes Pnext = Pw @ Pw (fused k_sq).
__global__ __launch_bounds__(256) void k_scan(const float* __restrict__ Min,
                                              float* __restrict__ Mout,
                                              const float* __restrict__ Pw,
                                              int stride,
                                              ushort_t* __restrict__ dstb,
                                              float* __restrict__ Pnext) {
    __shared__ float As[16][65];
    __shared__ float Bs[16][65];
    const int q    = blockIdx.z;
    const int row0 = blockIdx.y * 64;
    const int col0 = blockIdx.x * 64;
    const int tid  = threadIdx.x;
    const int tx = tid & 15, ty = tid >> 4;

    if (q == NQ) {   // fused squaring: Pnext = Pw @ Pw
        float acc[4][4] = {};
        for (int k0 = 0; k0 < ORD; k0 += 16) {
            for (int i = tid; i < 64 * 16; i += 256) {
                int m = i >> 4, kk = i & 15;
                As[kk][m] = Pw[(size_t)(row0 + m) * ORD + k0 + kk];
            }
            for (int i = tid; i < 16 * 64; i += 256) {
                int kk = i >> 6, n2 = i & 63;
                Bs[kk][n2] = Pw[(size_t)(k0 + kk) * ORD + col0 + n2];
            }
            __syncthreads();
            #pragma unroll
            for (int kk = 0; kk < 16; ++kk) {
                float a[4], b[4];
                #pragma unroll
                for (int i = 0; i < 4; ++i) a[i] = As[kk][ty * 4 + i];
                #pragma unroll
                for (int j = 0; j < 4; ++j) b[j] = Bs[kk][tx * 4 + j];
                #pragma unroll
                for (int i = 0; i < 4; ++i)
                    #pragma unroll
                    for (int j = 0; j < 4; ++j) acc[i][j] += a[i] * b[j];
            }
            __syncthreads();
        }
        #pragma unroll
        for (int i = 0; i < 4; ++i) {
            float4 v = make_float4(acc[i][0], acc[i][1], acc[i][2], acc[i][3]);
            *(float4*)&Pnext[(size_t)(row0 + ty * 4 + i) * ORD + col0 + tx * 4] = v;
        }
        return;
    }

    const float* src = Min + (size_t)q * (BD * ORD);
    float*       dst = Mout + (size_t)q * (BD * ORD);
    ushort_t*    db  = dstb ? dstb + (size_t)q * (BD * ORD) : nullptr;

    if (q - stride < 1) {   // nothing to add (M_0 = 0 source) -> copy through
        for (int i = tid; i < 64 * 64; i += 256) {
            int r = i >> 6, c = i & 63;
            size_t off = (size_t)(row0 + r) * ORD + col0 + c;
            float v = src[off];
            if (db) db[off] = f2bf(v); else dst[off] = v;
        }
        return;
    }

    const float* Ag = Min + (size_t)(q - stride) * (BD * ORD);

    float acc[4][4] = {};
    for (int k0 = 0; k0 < ORD; k0 += 16) {
        for (int i = tid; i < 64 * 16; i += 256) {
            int m = i >> 4, kk = i & 15;
            As[kk][m] = Ag[(size_t)(row0 + m) * ORD + k0 + kk];
        }
        for (int i = tid; i < 16 * 64; i += 256) {
            int kk = i >> 6, n2 = i & 63;
            Bs[kk][n2] = Pw[(size_t)(k0 + kk) * ORD + col0 + n2];
        }
        __syncthreads();
        #pragma unroll
        for (int kk = 0; kk < 16; ++kk) {
            float a[4], b[4];
            #pragma unroll
            for (int i = 0; i < 4; ++i) a[i] = As[kk][ty * 4 + i];
            #pragma unroll
            for (int j = 0; j < 4; ++j) b[j] = Bs[kk][tx * 4 + j];
            #pragma unroll
            for (int i = 0; i < 4; ++i)
                #pragma unroll
                for (int j = 0; j < 4; ++j) acc[i][j] += a[i] * b[j];
        }
        __syncthreads();
    }
    #pragma unroll
    for (int i = 0; i < 4; ++i) {
        int row = row0 + ty * 4 + i;
        #pragma unroll
        for (int j = 0; j < 4; ++j) {
            int o = col0 + tx * 4 + j;
            size_t off = (size_t)row * ORD + o;
            float val = acc[i][j] + src[off];
            if (db) db[off] = f2bf(val); else dst[off] = val;
        }
    }
}

// ====== MFMA GEMM 1 (m97 single-buffer): mbuf = [U2chunk | Mq] @ [Ptrib ; Apb]
// LDS-transpose epilogue for coalesced 256B stores.
__global__ __launch_bounds__(256) void k_gemm24(const ushort_t* __restrict__ U2b,
                                                const ushort_t* __restrict__ Mqb,
                                                const ushort_t* __restrict__ Ptrib,
                                                const ushort_t* __restrict__ Apb,
                                                ushort_t* __restrict__ mbuf,
                                                int gbase, int nrows) {
    __shared__ ushort_t As[128 * 32];
    __shared__ ushort_t Bs[128 * 32];
    __shared__ ushort_t st[128][136];
    const int q       = blockIdx.z;
    const int rowbase = blockIdx.y * 128;
    const int colbase = blockIdx.x * 128;
    const int tid  = threadIdx.x;
    const int lane = tid & 63;
    const int wid  = tid >> 6;
    const int wr = wid >> 1, wc = wid & 1;
    const int lr = lane & 15, lk = (lane >> 4) * 8;

    f32x4 acc[4][4];
    #pragma unroll
    for (int m = 0; m < 4; ++m)
        #pragma unroll
        for (int n = 0; n < 4; ++n) acc[m][n] = 0.f;

    for (int s = 0; s < KTOT24 / 32; ++s) {
        const int k0 = s * 32;
        #pragma unroll
        for (int i = 0; i < 2; ++i) {
            const int ub = (wid * 2 + i) * 64;       // unit base (wave-uniform)
            const int u  = ub + lane;                // 16B unit 0..511
            const int row = u >> 2, cb = (u & 3) * 8;
            int gr = rowbase + row;
            if (gr >= nrows) gr = nrows - 1;
            const ushort_t *ga, *gb;
            if (k0 < CH) {
                ga = &U2b[(size_t)(gbase + gr) * T + q * CH + k0 + cb];
                gb = &Ptrib[(size_t)(colbase + row) * CH + k0 + cb];
            } else {
                ga = &Mqb[((size_t)q * BD + gbase + gr) * ORD + (k0 - CH) + cb];
                gb = &Apb[(size_t)(colbase + row) * ORD + (k0 - CH) + cb];
            }
            gl_lds16(ga, &As[ub * 8]);
            gl_lds16(gb, &Bs[ub * 8]);
        }
        __syncthreads();
        bf16x8 af[4], bfv[4];
        #pragma unroll
        for (int m = 0; m < 4; ++m)
            af[m]  = *(const bf16x8*)&As[(wr * 64 + m * 16 + lr) * 32 + lk];
        #pragma unroll
        for (int n = 0; n < 4; ++n)
            bfv[n] = *(const bf16x8*)&Bs[(wc * 64 + n * 16 + lr) * 32 + lk];
        #pragma unroll
        for (int m = 0; m < 4; ++m)
            #pragma unroll
            for (int n = 0; n < 4; ++n)
                acc[m][n] = __builtin_amdgcn_mfma_f32_16x16x32_bf16(af[m], bfv[n], acc[m][n], 0, 0, 0);
        __syncthreads();
    }

    // ---- epilogue: acc -> LDS tile -> coalesced 256B stores ----
    #pragma unroll
    for (int m = 0; m < 4; ++m)
        #pragma unroll
        for (int n = 0; n < 4; ++n)
            #pragma unroll
            for (int r = 0; r < 4; ++r)
                st[wr * 64 + m * 16 + ((lane >> 4) << 2) + r]
                  [wc * 64 + n * 16 + lr] = f2bf(acc[m][n][r]);
    __syncthreads();

    const int c     = colbase >> 8;     // col tile lies within one c
    const int obase = colbase & 255;
    #pragma unroll
    for (int i = 0; i < 8; ++i) {
        int u  = tid + i * 256;          // 0..2047 16B units
        int rl = u >> 4, cb = (u & 15) * 8;
        int grow = rowbase + rl;
        if (grow < nrows) {
            int bl = grow >> 3, d = grow & 7;
            size_t addr = ((size_t)(bl * T + q * CH + c)) * DO + (d << 8) + obase + cb;
            *(us8*)&mbuf[addr] = *(const us8*)&st[rl][cb];
        }
    }
}

// ====== MFMA GEMM 2 (m97 single-buffer): out = tanh(mbuf @ Wh + bh) ======
// 1-D grid = 4*gy blocks; XCD swizzle keeps a row-panel's 4 col-tiles on one XCD.
__global__ __launch_bounds__(256) void k_gemm5(const ushort_t* __restrict__ mbuf,
                                               const ushort_t* __restrict__ Whbt,
                                               const float* __restrict__ bh,
                                               float* __restrict__ out, int gy) {
    __shared__ ushort_t As[128 * 32];
    __shared__ ushort_t Bs[128 * 32];
    int wg = blockIdx.x;
    int bx, by;
    if ((gy & 7) == 0) {
        int xcd = wg & 7, j = wg >> 3;
        int rpx = gy >> 3;                 // row panels per XCD
        by = xcd * rpx + (j >> 2);
        bx = j & 3;
    } else { bx = wg & 3; by = wg >> 2; }
    const int rowbase = by * 128;
    const int colbase = bx * 128;
    const int tid  = threadIdx.x;
    const int lane = tid & 63;
    const int wid  = tid >> 6;
    const int wr = wid >> 1, wc = wid & 1;
    const int lr = lane & 15, lk = (lane >> 4) * 8;

    f32x4 acc[4][4];
    #pragma unroll
    for (int m = 0; m < 4; ++m)
        #pragma unroll
        for (int n = 0; n < 4; ++n) acc[m][n] = 0.f;

    for (int s = 0; s < DO / 32; ++s) {
        const int k0 = s * 32;
        #pragma unroll
        for (int i = 0; i < 2; ++i) {
            const int ub = (wid * 2 + i) * 64;
            const int u  = ub + lane;
            const int row = u >> 2, cb = (u & 3) * 8;
            gl_lds16(&mbuf[(size_t)(rowbase + row) * DO + k0 + cb], &As[ub * 8]);
            gl_lds16(&Whbt[(size_t)(colbase + row) * DO + k0 + cb], &Bs[ub * 8]);
        }
        __syncthreads();
        bf16x8 af[4], bfv[4];
        #pragma unroll
        for (int m = 0; m < 4; ++m)
            af[m]  = *(const bf16x8*)&As[(wr * 64 + m * 16 + lr) * 32 + lk];
        #pragma unroll
        for (int n = 0; n < 4; ++n)
            bfv[n] = *(const bf16x8*)&Bs[(wc * 64 + n * 16 + lr) * 32 + lk];
        #pragma unroll
        for (int m = 0; m < 4; ++m)
            #pragma unroll
            for (int n = 0; n < 4; ++n)
                acc[m][n] = __builtin_amdgcn_mfma_f32_16x16x32_bf16(af[m], bfv[n], acc[m][n], 0, 0, 0);
        __syncthreads();
    }

    #pragma unroll
    for (int m = 0; m < 4; ++m) {
        #pragma unroll
        for (int n = 0; n < 4; ++n) {
            int col = colbase + wc * 64 + n * 16 + lr;
            float bias = bh[col];
            #pragma unroll
            for (int r = 0; r < 4; ++r) {
                int grow = rowbase + wr * 64 + m * 16 + ((lane >> 4) << 2) + r;
                out[(size_t)grow * HID + col] = tanhf(acc[m][n][r] + bias);
            }
        }
    }
}

// ---------------- launch ----------------
extern "C" void kernel_launch(void* const* d_in, const int* in_sizes, int n_in,
                              void* d_out, int out_size, void* d_ws, size_t ws_size,
                              hipStream_t stream) {
    const float* x    = (const float*)d_in[0];
    const float* kern = (const float*)d_in[1];
    const float* Wh   = (const float*)d_in[2];
    const float* bh   = (const float*)d_in[3];
    const float* A    = (const float*)d_in[4];
    const float* Brow = (const float*)d_in[5];
    float* out = (float*)d_out;

    char* base = (char*)d_ws;
    float*    U2    = (float*)(base + OFF_U2);
    float*    P     = (float*)(base + OFF_P);
    float*    Apow  = (float*)(base + OFF_APOW);
    float*    MqA   = (float*)(base + OFF_MQ);
    float*    Lend  = (float*)(base + OFF_LEND);
    ushort_t* U2b   = (ushort_t*)(base + OFF_U2B);
    ushort_t* Ptrib = (ushort_t*)(base + OFF_PTRB);
    ushort_t* Apb   = (ushort_t*)(base + OFF_APB);
    ushort_t* Whbt  = (ushort_t*)(base + OFF_WHBT);
    ushort_t* Mqb   = (ushort_t*)(base + OFF_MQB);
    ushort_t* mbuf  = (ushort_t*)(base + OFF_MBUF);

    // scratch for higher powers (regions dead by the time they're written)
    float* A64  = Apow + (size_t)CH * OO;  // A^64 (slot 64)
    float* A128 = Apow;                    // Apow slot 0 (unused)
    float* A256 = U2;                      // U2 f32 dead after k_lend
    float* A512 = U2 + OO;

    // choose largest batch group whose bf16 mbuf fits
    int G = 1;
    for (int g = 32; g >= 1; g >>= 1) {
        if (OFF_MBUF + (size_t)g * T * DO * 2 <= ws_size) { G = g; break; }
    }
    const int ngroups = BSZ / G;

    // U projection (f32 + bf16)
    k_u<<<dim3(BSZ * (T / 32)), 256, 0, stream>>>(x, kern, U2, U2b);

    // A -> Apow[1] + Apb[0]; powers 2..64 by doubling (f32 + bf16 transpose)
    k_copyAT<<<dim3(8, 8), 256, 0, stream>>>(A, Apow, Apb);
    for (int n = 1; n < CH; n <<= 1)
        k_pow<<<dim3(4, 4, n), 256, 0, stream>>>(Apow, n, Apb);

    // P rows (f32), bf16 operand prep
    k_p<<<dim3(CH), 256, 0, stream>>>(Brow, Apow, P);
    k_ptrib<<<dim3((CH * ORD * CH) / 256), 256, 0, stream>>>(P, Ptrib);
    k_whbt<<<dim3(DO / 32, HID / 32), 256, 0, stream>>>(Wh, Whbt);

    // chunk-end partials (f32) + scan init — last use of U2 f32
    k_lend<<<dim3(ORD / 64, BD / 64, NQ), 256, 0, stream>>>(U2, P, Lend, MqA);

    // Hillis-Steele matrix scan (f32), strides 1,2,4,8; passes 1-3 also
    // square Pw -> next power (fused k_sq at blockIdx.z == NQ).
    k_scan<<<dim3(4, 4, NQ + 1), 256, 0, stream>>>(MqA, Lend, A64, 1, nullptr, A128);
    k_scan<<<dim3(4, 4, NQ + 1), 256, 0, stream>>>(Lend, MqA, A128, 2, nullptr, A256);
    k_scan<<<dim3(4, 4, NQ + 1), 256, 0, stream>>>(MqA, Lend, A256, 4, nullptr, A512);
    k_scan<<<dim3(4, 4, NQ), 256, 0, stream>>>(Lend, MqA, A512, 8, Mqb, nullptr);

    // per batch-group: MFMA m-materialization + MFMA output GEMM
    for (int g = 0; g < ngroups; ++g) {
        const int gbase = g * G * MD;
        const int nrows = G * MD;
        const int gy24  = (nrows + 127) / 128;
        k_gemm24<<<dim3((CH * ORD) / 128, gy24, NQ), 256, 0, stream>>>(
            U2b, Mqb, Ptrib, Apb, mbuf, gbase, nrows);
        const int gy = (G * T) / 128;
        k_gemm5<<<dim3(4 * gy), 256, 0, stream>>>(
            mbuf, Whbt, bh, out + (size_t)g * G * T * HID, gy);
    }
}